// Round 11
// baseline (283.695 us; speedup 1.0000x reference)
//
#include <hip/hip_runtime.h>
#include <hip/hip_bf16.h>
#include <cstdint>
#include <cstddef>

#define TT 1024
#define NN 64
#define CC 512
#define SS 64
#define TCH 32  // t-chunk per block
#define NEGF (-1e30f)
#define LN2F 0.6931471805599453f
#define SMALLE (-0x40000000)

__device__ __forceinline__ float exp2i(float x) { return __builtin_amdgcn_exp2f(x); }
__device__ __forceinline__ float log2i(float x) { return __builtin_amdgcn_logf(x); }

__device__ __forceinline__ float ldx(float x, int e) {
#if __has_builtin(__builtin_amdgcn_ldexpf)
  return __builtin_amdgcn_ldexpf(x, e);
#else
  return ldexpf(x, e);
#endif
}

// log-sum-exp in log2 domain (final combine only)
__device__ __forceinline__ float lse2(float x, float y) {
  float m = fmaxf(x, y);
  float d = fabsf(x - y);
  return m + log2i(1.0f + exp2i(-d));
}
__device__ __forceinline__ float lse3(float x, float y, float z) {
  float m = fmaxf(fmaxf(x, y), z);
  float s = exp2i(x - m) + exp2i(y - m) + exp2i(z - m);
  return m + log2i(s);
}

// lane l gets lane l-1's value; lane 0 gets `oldv` (DPP wave_shr:1) — HW-verified R2/R5/R7.
__device__ __forceinline__ float dpp_shr1(float x, float oldv) {
  int r = __builtin_amdgcn_update_dpp(__float_as_int(oldv), __float_as_int(x),
                                      0x138, 0xF, 0xF, false);
  return __int_as_float(r);
}
__device__ __forceinline__ int dpp_shr1_i(int x, int oldv) {
  return __builtin_amdgcn_update_dpp(oldv, x, 0x138, 0xF, 0xF, false);
}

// one u64-max DPP reduction step (old = self: uncovered lanes keep own key)
template <int CTRL>
__device__ __forceinline__ unsigned long long dpp_umax64(unsigned long long k) {
  const int lo = (int)(unsigned)k;
  const int hi = (int)(unsigned)(k >> 32);
  const int slo = __builtin_amdgcn_update_dpp(lo, lo, CTRL, 0xF, 0xF, false);
  const int shi = __builtin_amdgcn_update_dpp(hi, hi, CTRL, 0xF, 0xF, false);
  const unsigned long long o =
      ((unsigned long long)(unsigned)shi << 32) | (unsigned)slo;
  return o > k ? o : k;
}

// argmax key: monotone for log-softmax values (all < 0). Low bits: 511-idx
// so max picks the FIRST index on exact ties.  [HW-verified R7]
__device__ __forceinline__ unsigned long long akey(float v, int idx) {
  return ((unsigned long long)(~__float_as_uint(v)) << 32) |
         (unsigned)(511 - idx);
}
__device__ __forceinline__ unsigned long long umax64(unsigned long long a,
                                                     unsigned long long b) {
  return a > b ? a : b;
}

// f32 -> bf16 RNE (inputs are finite positive probs)
__device__ __forceinline__ unsigned bf16rne(float f) {
  unsigned u = __float_as_uint(f);
  return (u + 0x7FFFu + ((u >> 16) & 1u)) >> 16;
}

// bf16 halves of a u32 -> f32
#define BF_LO(r) __uint_as_float((r) << 16)
#define BF_HI(r) __uint_as_float((r) & 0xFFFF0000u)

// ---------------------------------------------------------------------------
// Single fused kernel. Phase 1 (all 2048 blocks): rowpass for (n, t-chunk) —
// DPP-u64 argmax -> pred; bf16 linear target weights transposed to
// Wt16[(n*64+s)][t]; blank f32 -> Wb[n][t]. Then device fence + per-n arrival
// counter; the LAST of the 32 blocks for n (atomicAdd returns 31) runs
// Phase 2: the R9-verified CTC fwd/bwd + penalty + combine for that n, and
// atomicAdds its contribution into out[0]. No spinning — deadlock-free, no
// dispatch-order assumption (G16-safe: device-scope fences + atomics).
// ---------------------------------------------------------------------------
__global__ __launch_bounds__(256) void k_fused(
    const float* __restrict__ lp, const int* __restrict__ targets,
    const int* __restrict__ ilen, const int* __restrict__ tlen,
    unsigned short* __restrict__ Wt16, float* __restrict__ Wb,
    int* __restrict__ pred, int* __restrict__ cnt, float* __restrict__ out) {
  __shared__ float rows[4][CC];
  __shared__ float Gs[TCH][65];
  __shared__ float Gsb[TCH];
  __shared__ float Bo[64], Be[64], BTs, penv;
  __shared__ int ts[SS];
  __shared__ int winls;
  const int tid = threadIdx.x;
  const int wid = tid >> 6;
  const int l = tid & 63;
  const int n = blockIdx.x & 63;
  const int tc = blockIdx.x >> 6;  // t-chunk of 32

  // ======================= Phase 1: rowpass =======================
  {
    const int tgt = targets[n * SS + l];
    for (int i = 0; i < 8; ++i) {
      const int tl = wid * 8 + i;  // local t in [0,32)
      const int t = tc * TCH + tl;
      const float* row = lp + ((size_t)t * NN + n) * CC;
      const float4 v0 = ((const float4*)row)[l];
      const float4 v1 = ((const float4*)row)[l + 64];
      ((float4*)rows[wid])[l] = v0;
      ((float4*)rows[wid])[l + 64] = v1;

      const unsigned long long ka =
          umax64(akey(v0.x, 4 * l), akey(v0.y, 4 * l + 1));
      const unsigned long long kb =
          umax64(akey(v0.z, 4 * l + 2), akey(v0.w, 4 * l + 3));
      const unsigned long long kc =
          umax64(akey(v1.x, 256 + 4 * l), akey(v1.y, 256 + 4 * l + 1));
      const unsigned long long kd =
          umax64(akey(v1.z, 256 + 4 * l + 2), akey(v1.w, 256 + 4 * l + 3));
      unsigned long long k = umax64(umax64(ka, kb), umax64(kc, kd));
      k = dpp_umax64<0x111>(k);  // row_shr:1
      k = dpp_umax64<0x112>(k);  // row_shr:2
      k = dpp_umax64<0x114>(k);  // row_shr:4
      k = dpp_umax64<0x118>(k);  // row_shr:8
      k = dpp_umax64<0x142>(k);  // row_bcast:15
      k = dpp_umax64<0x143>(k);  // row_bcast:31

      const float gv = rows[wid][tgt];
      Gs[tl][l] = __expf(gv);  // linear p(tgt)
      if (l == 63) pred[n * TT + t] = 511 - (int)(unsigned)k;
      if (l == 0) Gsb[tl] = __expf(v0.x);  // linear p(blank)
    }
    __syncthreads();

    // transpose store: thread (s = tid>>2, q2 = tid&3) -> 4 consecutive
    // lanes cover one strip's 64 contiguous bytes.
    const int s = tid >> 2;
    const int q2 = tid & 3;
    uint4 wv;
    wv.x = bf16rne(Gs[q2 * 8 + 0][s]) | (bf16rne(Gs[q2 * 8 + 1][s]) << 16);
    wv.y = bf16rne(Gs[q2 * 8 + 2][s]) | (bf16rne(Gs[q2 * 8 + 3][s]) << 16);
    wv.z = bf16rne(Gs[q2 * 8 + 4][s]) | (bf16rne(Gs[q2 * 8 + 5][s]) << 16);
    wv.w = bf16rne(Gs[q2 * 8 + 6][s]) | (bf16rne(Gs[q2 * 8 + 7][s]) << 16);
    *(uint4*)(Wt16 + (size_t)(n * 64 + s) * TT + tc * TCH + q2 * 8) = wv;
    if (tid < TCH) Wb[(size_t)n * TT + tc * TCH + tid] = Gsb[tid];
  }

  // =============== arrival: last block of this n proceeds ===============
  __threadfence();  // every thread: publish phase-1 stores device-wide
  __syncthreads();
  if (tid == 0) winls = (atomicAdd(&cnt[n], 1) == 31) ? 1 : 0;
  __syncthreads();
  if (!winls) return;  // uniform per block: all 4 waves exit together
  __threadfence();     // acquire side: see all 32 blocks' stores

  // ======================= Phase 2: CTC for n =======================
  const int Lm1 = __builtin_amdgcn_readfirstlane(ilen[n]) - 1;
  const int Ltg = __builtin_amdgcn_readfirstlane(tlen[n]);

  float fe0 = NEGF, fe1 = NEGF, fa0 = NEGF;
  float s0L = NEGF, s1L = NEGF;  // snapshot (Lm1 < 512), log2

  if (wid == 0) {
    // ---------------- forward wave: t = 0 .. 511 ----------------
    const int tgt = targets[n * SS + l];
    const int tprev = __shfl_up(tgt, 1);
    const float skipf = ((l == 0) || (tgt != tprev)) ? 1.0f : 0.0f;
    const uint2* bt = (const uint2*)(Wt16 + (size_t)(n * 64 + l) * TT);
    const float4* bb = (const float4*)(Wb + (size_t)n * TT);
    uint2 ring[8];
    float4 ringb[8];
#pragma unroll
    for (int i = 0; i < 8; ++i) {
      ring[i] = bt[i];
      ringb[i] = bb[i];
    }

    float Q0 = 0.0f, Q1 = 0.0f, Qa = 1.0f;
    int E = 0, Ea = 0, dEnb = 0, dEa = 0;
    float sQ0 = 0.0f, sQ1 = 0.0f;
    int sE = 0;

#define FSTEP(WTv, WBv)                              \
    {                                                \
      const float a0f = ldx(Qa, dEa);                \
      const float up0 = dpp_shr1(Q0, a0f);           \
      const float up1 = dpp_shr1(Q1, 0.0f);          \
      const float uu = fmaf(skipf, up1, up0);        \
      const float us = ldx(uu, dEnb);                \
      const float n1 = (Q1 + us) * (WTv);            \
      const float n0 = (Q0 + Q1) * (WBv);            \
      Qa *= (WBv);                                   \
      Q0 = n0;                                       \
      Q1 = n1;                                       \
    }
#define FRENORM                                               \
    {                                                         \
      const float mq = fmaxf(Q0, Q1);                         \
      const int eo = (mq > 0.0f)                              \
          ? (E + (((__float_as_int(mq) >> 23) & 255) - 127))  \
          : SMALLE;                                           \
      const int en = dpp_shr1_i(eo, SMALLE);                  \
      int En = (eo > en) ? eo : en;                           \
      if (En == SMALLE) En = E;                               \
      const int sh = E - En;                                  \
      Q0 = ldx(Q0, sh);                                       \
      Q1 = ldx(Q1, sh);                                       \
      E = En;                                                 \
      const int Eup = dpp_shr1_i(E, E);                       \
      dEnb = Eup - E;                                         \
      const int exa = ((__float_as_int(Qa) >> 23) & 255) - 127; \
      Ea += exa;                                              \
      Qa = ldx(Qa, -exa);                                     \
      dEa = Ea - E;                                           \
    }

    for (int g = 0; g < 16; ++g) {
#pragma unroll
      for (int ci = 0; ci < 8; ++ci) {
        const int c = g * 8 + ci;
        const uint2 wt4 = ring[ci];
        const float4 wb4 = ringb[ci];
        ring[ci] = bt[c + 8];  // overshoot stays inside d_ws
        ringb[ci] = bb[c + 8];
        if (__builtin_expect((unsigned)(Lm1 - c * 4) < 4u, 0)) {
          FSTEP(BF_LO(wt4.x), wb4.x);
          if (c * 4 + 0 == Lm1) { sQ0 = Q0; sQ1 = Q1; sE = E; }
          FSTEP(BF_HI(wt4.x), wb4.y);
          if (c * 4 + 1 == Lm1) { sQ0 = Q0; sQ1 = Q1; sE = E; }
          FSTEP(BF_LO(wt4.y), wb4.z);
          if (c * 4 + 2 == Lm1) { sQ0 = Q0; sQ1 = Q1; sE = E; }
          FSTEP(BF_HI(wt4.y), wb4.w);
          if (c * 4 + 3 == Lm1) { sQ0 = Q0; sQ1 = Q1; sE = E; }
        } else {
          FSTEP(BF_LO(wt4.x), wb4.x);
          FSTEP(BF_HI(wt4.x), wb4.y);
          FSTEP(BF_LO(wt4.y), wb4.z);
          FSTEP(BF_HI(wt4.y), wb4.w);
        }
        FRENORM;
      }
    }
#undef FSTEP
#undef FRENORM
    const float fE = (float)E;
    fe0 = (Q0 > 0.0f) ? (log2i(Q0) + fE) : NEGF;
    fe1 = (Q1 > 0.0f) ? (log2i(Q1) + fE) : NEGF;
    fa0 = (Qa > 0.0f) ? (log2i(Qa) + (float)Ea) : NEGF;
    s0L = (sQ0 > 0.0f) ? (log2i(sQ0) + (float)sE) : NEGF;
    s1L = (sQ1 > 0.0f) ? (log2i(sQ1) + (float)sE) : NEGF;
  } else if (wid == 1) {
    // ---------------- backward wave: t = 1023 .. 512 ----------------
    const int m = 63 - l;
    const int tm = targets[n * SS + m];
    const int tmp = __shfl_up(tm, 1);  // lane l-1 holds m+1
    const float skipbf = ((l > 0) && (tm != tmp)) ? 1.0f : 0.0f;
    const uint2* bt = (const uint2*)(Wt16 + (size_t)(n * 64 + m) * TT);
    const float4* bb = (const float4*)(Wb + (size_t)n * TT);
    uint2 ring[8];
    float4 ringb[8];
#pragma unroll
    for (int i = 0; i < 8; ++i) {
      ring[i] = bt[255 - i];
      ringb[i] = bb[255 - i];
    }

    float Qd0 = 0.0f, Qd1 = 0.0f, QaT = 0.0f;
    int Eb = 0, EaT = 0, dEnb = 0, dEa = 0;

#define BSTEP(WTv, WBv)                              \
    {                                                \
      const float aTf = ldx(QaT, dEa);               \
      const float nd0 = dpp_shr1(Qd0, aTf);          \
      const float nd1 = dpp_shr1(Qd1, 0.0f);         \
      const float uu = fmaf(skipbf, nd1, nd0);       \
      const float us = ldx(uu, dEnb);                \
      const float n1 = (Qd1 + us) * (WTv);           \
      const float n0 = (Qd0 + Qd1) * (WBv);          \
      QaT *= (WBv);                                  \
      Qd0 = n0;                                      \
      Qd1 = n1;                                      \
    }
#define BINIT(WTv, WBv)                              \
    {                                                \
      Qd0 = (m == Ltg) ? (WBv) : 0.0f;               \
      Qd1 = (m == Ltg - 1) ? (WTv) : 0.0f;           \
      QaT = (Ltg == 64) ? (WBv) : 0.0f;              \
      Eb = 0; EaT = 0; dEnb = 0; dEa = 0;            \
    }
#define BRENORM                                               \
    {                                                         \
      const float mq = fmaxf(Qd0, Qd1);                       \
      const int eo = (mq > 0.0f)                              \
          ? (Eb + (((__float_as_int(mq) >> 23) & 255) - 127)) \
          : SMALLE;                                           \
      const int en = dpp_shr1_i(eo, SMALLE);                  \
      int En = (eo > en) ? eo : en;                           \
      if (En == SMALLE) En = Eb;                              \
      const int sh = Eb - En;                                 \
      Qd0 = ldx(Qd0, sh);                                     \
      Qd1 = ldx(Qd1, sh);                                     \
      Eb = En;                                                \
      const int Eup = dpp_shr1_i(Eb, Eb);                     \
      dEnb = Eup - Eb;                                        \
      if (QaT > 0.0f) {                                       \
        const int exa = ((__float_as_int(QaT) >> 23) & 255) - 127; \
        EaT += exa;                                           \
        QaT = ldx(QaT, -exa);                                 \
      }                                                       \
      dEa = EaT - Eb;                                         \
    }

    for (int g = 0; g < 16; ++g) {
#pragma unroll
      for (int ci = 0; ci < 8; ++ci) {
        const int cs = g * 8 + ci;
        const uint2 wt4 = ring[ci];
        const float4 wb4 = ringb[ci];
        ring[ci] = bt[255 - cs - 8];
        ringb[ci] = bb[255 - cs - 8];
        const int thi = 1023 - 4 * cs;
        if (__builtin_expect((unsigned)(thi - Lm1) < 4u, 0)) {
          if (thi - 0 == Lm1) BINIT(BF_HI(wt4.y), wb4.w) else BSTEP(BF_HI(wt4.y), wb4.w);
          if (thi - 1 == Lm1) BINIT(BF_LO(wt4.y), wb4.z) else BSTEP(BF_LO(wt4.y), wb4.z);
          if (thi - 2 == Lm1) BINIT(BF_HI(wt4.x), wb4.y) else BSTEP(BF_HI(wt4.x), wb4.y);
          if (thi - 3 == Lm1) BINIT(BF_LO(wt4.x), wb4.x) else BSTEP(BF_LO(wt4.x), wb4.x);
        } else {
          BSTEP(BF_HI(wt4.y), wb4.w);
          BSTEP(BF_LO(wt4.y), wb4.z);
          BSTEP(BF_HI(wt4.x), wb4.y);
          BSTEP(BF_LO(wt4.x), wb4.x);
        }
        BRENORM;
      }
    }
#undef BSTEP
#undef BINIT
#undef BRENORM

    // convert to log2; boundary combine step (R4-verified shape)
    const float fEb = (float)Eb;
    const float d0L = (Qd0 > 0.0f) ? (log2i(Qd0) + fEb) : NEGF;
    const float d1L = (Qd1 > 0.0f) ? (log2i(Qd1) + fEb) : NEGF;
    const float aTL = (QaT > 0.0f) ? (log2i(QaT) + (float)EaT) : NEGF;
    const float nd0 = dpp_shr1(d0L, aTL);
    const float nd1 = dpp_shr1(d1L, NEGF);
    const float skz = ((l > 0) && (tm != tmp)) ? nd1 : NEGF;
    Bo[m] = lse3(d1L, nd0, skz);
    Be[m] = lse2(d0L, d1L);
    if (l == 0) BTs = aTL;
  } else if (wid == 2) {
    // ---------------- penalty wave ----------------
    const int tv = targets[n * SS + l];
    const bool tf = (l < Ltg) && (tv >= 1) && (tv <= 8);
    const unsigned long long tmk = __ballot(tf);
    const int tcnt = __popcll(tmk);
    if (tf) ts[__popcll(tmk & ((1ull << l) - 1ull))] = tv;

    const int L_in = Lm1 + 1;
    int mism = 0;
    int prevc = -1;
    int base = 0;
#pragma unroll 4
    for (int c = 0; c < TT / 64; ++c) {
      const int t = c * 64 + l;
      int p = pred[n * TT + t];
      if (t >= L_in) p = 0;
      int pp = __shfl_up(p, 1);
      if (l == 0) pp = prevc;
      const bool keep = (p != pp) && (p >= 1) && (p <= 8);
      const unsigned long long mk = __ballot(keep);
      const int pos = base + __popcll(mk & ((1ull << l) - 1ull));
      if (keep && (pos >= tcnt || ts[pos] != p)) mism = 1;
      base += __popcll(mk);
      prevc = __shfl(p, 63);
    }
    if (base != tcnt) mism = 1;
    if (__any(mism)) mism = 1;
    if (l == 0) penv = mism ? 1.0f : 0.0f;
  }
  // wave 3: passthrough to the barrier

  __syncthreads();

  if (wid == 0) {
    float loss;
    if (Lm1 >= 512) {
      const float to_ = fe1 + Bo[l];                         // u = 2l+1
      const float te_ = fe0 + ((l < 63) ? Be[l + 1] : BTs);  // u = 2l+2
      const float t0_ = (l == 0) ? (fa0 + Be[0]) : NEGF;     // u = 0
      float mx = fmaxf(fmaxf(to_, te_), t0_);
#pragma unroll
      for (int off = 32; off; off >>= 1) mx = fmaxf(mx, __shfl_xor(mx, off));
      float s = exp2i(to_ - mx) + exp2i(te_ - mx) +
                ((l == 0) ? exp2i(t0_ - mx) : 0.0f);
#pragma unroll
      for (int off = 32; off; off >>= 1) s += __shfl_xor(s, off);
      loss = -(mx + log2i(s)) * LN2F;
    } else {
      const float pA = __shfl(s0L, Ltg - 1);  // alpha[2*Ltg]
      const float pB = __shfl(s1L, Ltg - 1);  // alpha[2*Ltg-1]
      loss = -lse2(pA, pB) * LN2F;
    }
    if (loss > 1e20f) loss = 0.0f;
    if (!(loss <= 1e20f)) loss = 0.0f;  // NaN guard
    if (l == 0) atomicAdd(out, (loss + penv) * (1.0f / NN));
  }
}

extern "C" void kernel_launch(void* const* d_in, const int* in_sizes, int n_in,
                              void* d_out, int out_size, void* d_ws,
                              size_t ws_size, hipStream_t stream) {
  const float* log_probs = (const float*)d_in[0];  // (T,N,C) f32
  const int* targets = (const int*)d_in[1];        // (N,S) i32
  const int* input_lengths = (const int*)d_in[2];  // (N,) i32
  const int* target_lengths = (const int*)d_in[3]; // (N,) i32
  float* out = (float*)d_out;

  // workspace layout
  unsigned short* Wt16 = (unsigned short*)d_ws;      // [N*64][T] bf16 (8.4 MB)
  float* Wb = (float*)(Wt16 + (size_t)NN * 64 * TT); // [N][T] f32 (256 KB)
  int* pred = (int*)(Wb + (size_t)NN * TT);          // [N][T] i32 (256 KB)
  int* cnt = pred + (size_t)NN * TT;                 // [N] i32 arrival counters

  hipMemsetAsync(out, 0, sizeof(float), stream);
  hipMemsetAsync(cnt, 0, NN * sizeof(int), stream);
  k_fused<<<NN * (TT / TCH), 256, 0, stream>>>(
      log_probs, targets, input_lengths, target_lengths, Wt16, Wb, pred, cnt,
      out);
}

// Round 12
// 53.926 us; speedup vs baseline: 5.2608x; 5.2608x over previous
//
#include <hip/hip_runtime.h>
#include <hip/hip_bf16.h>
#include <cstdint>
#include <cstddef>

#define TT 1024
#define NN 64
#define CC 512
#define SS 64
#define TCH 32  // t-chunk per rowpass block
#define NEGF (-1e30f)
#define LN2F 0.6931471805599453f
#define SMALLE (-0x40000000)

__device__ __forceinline__ float exp2i(float x) { return __builtin_amdgcn_exp2f(x); }
__device__ __forceinline__ float log2i(float x) { return __builtin_amdgcn_logf(x); }

__device__ __forceinline__ float ldx(float x, int e) {
#if __has_builtin(__builtin_amdgcn_ldexpf)
  return __builtin_amdgcn_ldexpf(x, e);
#else
  return ldexpf(x, e);
#endif
}

// log-sum-exp in log2 domain (final combine only)
__device__ __forceinline__ float lse2(float x, float y) {
  float m = fmaxf(x, y);
  float d = fabsf(x - y);
  return m + log2i(1.0f + exp2i(-d));
}
__device__ __forceinline__ float lse3(float x, float y, float z) {
  float m = fmaxf(fmaxf(x, y), z);
  float s = exp2i(x - m) + exp2i(y - m) + exp2i(z - m);
  return m + log2i(s);
}

// lane l gets lane l-1's value; lane 0 gets `oldv` (DPP wave_shr:1) — HW-verified R2/R5/R7.
__device__ __forceinline__ float dpp_shr1(float x, float oldv) {
  int r = __builtin_amdgcn_update_dpp(__float_as_int(oldv), __float_as_int(x),
                                      0x138, 0xF, 0xF, false);
  return __int_as_float(r);
}
__device__ __forceinline__ int dpp_shr1_i(int x, int oldv) {
  return __builtin_amdgcn_update_dpp(oldv, x, 0x138, 0xF, 0xF, false);
}

// one u64-max DPP reduction step (old = self: uncovered lanes keep own key)
template <int CTRL>
__device__ __forceinline__ unsigned long long dpp_umax64(unsigned long long k) {
  const int lo = (int)(unsigned)k;
  const int hi = (int)(unsigned)(k >> 32);
  const int slo = __builtin_amdgcn_update_dpp(lo, lo, CTRL, 0xF, 0xF, false);
  const int shi = __builtin_amdgcn_update_dpp(hi, hi, CTRL, 0xF, 0xF, false);
  const unsigned long long o =
      ((unsigned long long)(unsigned)shi << 32) | (unsigned)slo;
  return o > k ? o : k;
}

// argmax key: monotone for log-softmax values (all < 0). Low bits: 511-idx
// so max picks the FIRST index on exact ties.  [HW-verified R7]
__device__ __forceinline__ unsigned long long akey(float v, int idx) {
  return ((unsigned long long)(~__float_as_uint(v)) << 32) |
         (unsigned)(511 - idx);
}
__device__ __forceinline__ unsigned long long umax64(unsigned long long a,
                                                     unsigned long long b) {
  return a > b ? a : b;
}

// f32 -> bf16 RNE (inputs are finite positive probs)
__device__ __forceinline__ unsigned bf16rne(float f) {
  unsigned u = __float_as_uint(f);
  return (u + 0x7FFFu + ((u >> 16) & 1u)) >> 16;
}

// bf16 halves of a u32 -> f32
#define BF_LO(r) __uint_as_float((r) << 16)
#define BF_HI(r) __uint_as_float((r) & 0xFFFF0000u)

// ---------------------------------------------------------------------------
// Kernel 1: fused row pass (R9-verbatim). Block = one n x 32 t, 4 waves x 8
// rows. DPP-u64 argmax -> pred; bf16 linear target weights transposed:
// Wt16[(n*64+s)][t]; blank f32 -> Wb[n][t]. Block 0 zeroes out[0].
// ---------------------------------------------------------------------------
__global__ __launch_bounds__(256) void k_rowpass(
    const float* __restrict__ lp, const int* __restrict__ targets,
    unsigned short* __restrict__ Wt16, float* __restrict__ Wb,
    int* __restrict__ pred, float* __restrict__ out) {
  __shared__ float rows[4][CC];
  __shared__ float Gs[TCH][65];
  __shared__ float Gsb[TCH];
  const int tid = threadIdx.x;
  const int wid = tid >> 6;
  const int l = tid & 63;
  const int n = blockIdx.x & 63;
  const int tc = blockIdx.x >> 6;  // t-chunk of 32

  if (blockIdx.x == 0 && tid == 0) out[0] = 0.0f;

  const int tgt = targets[n * SS + l];

  for (int i = 0; i < 8; ++i) {
    const int tl = wid * 8 + i;  // local t in [0,32)
    const int t = tc * TCH + tl;
    const float* row = lp + ((size_t)t * NN + n) * CC;
    const float4 v0 = ((const float4*)row)[l];
    const float4 v1 = ((const float4*)row)[l + 64];
    ((float4*)rows[wid])[l] = v0;
    ((float4*)rows[wid])[l + 64] = v1;

    const unsigned long long ka =
        umax64(akey(v0.x, 4 * l), akey(v0.y, 4 * l + 1));
    const unsigned long long kb =
        umax64(akey(v0.z, 4 * l + 2), akey(v0.w, 4 * l + 3));
    const unsigned long long kc =
        umax64(akey(v1.x, 256 + 4 * l), akey(v1.y, 256 + 4 * l + 1));
    const unsigned long long kd =
        umax64(akey(v1.z, 256 + 4 * l + 2), akey(v1.w, 256 + 4 * l + 3));
    unsigned long long k = umax64(umax64(ka, kb), umax64(kc, kd));
    k = dpp_umax64<0x111>(k);  // row_shr:1
    k = dpp_umax64<0x112>(k);  // row_shr:2
    k = dpp_umax64<0x114>(k);  // row_shr:4
    k = dpp_umax64<0x118>(k);  // row_shr:8
    k = dpp_umax64<0x142>(k);  // row_bcast:15
    k = dpp_umax64<0x143>(k);  // row_bcast:31

    const float gv = rows[wid][tgt];
    Gs[tl][l] = __expf(gv);  // linear p(tgt)
    if (l == 63) pred[n * TT + t] = 511 - (int)(unsigned)k;
    if (l == 0) Gsb[tl] = __expf(v0.x);  // linear p(blank)
  }
  __syncthreads();

  // transpose store: thread (l, q) packs 8 t's (bf16, 16B) for strip l
  const int q = tid >> 6;
  uint4 wv;
  wv.x = bf16rne(Gs[q * 8 + 0][l]) | (bf16rne(Gs[q * 8 + 1][l]) << 16);
  wv.y = bf16rne(Gs[q * 8 + 2][l]) | (bf16rne(Gs[q * 8 + 3][l]) << 16);
  wv.z = bf16rne(Gs[q * 8 + 4][l]) | (bf16rne(Gs[q * 8 + 5][l]) << 16);
  wv.w = bf16rne(Gs[q * 8 + 6][l]) | (bf16rne(Gs[q * 8 + 7][l]) << 16);
  *(uint4*)(Wt16 + (size_t)(n * 64 + l) * TT + tc * TCH + q * 8) = wv;
  if (tid < TCH) Wb[(size_t)n * TT + tc * TCH + tid] = Gsb[tid];
}

// ---------------------------------------------------------------------------
// Kernel 2: CTC fwd/bwd in LINEAR domain with per-lane exponent frames.
// Recursion macros R9-VERBATIM. The ONLY change: ring buffers are NAMED
// variables (r0..r7 / q0..q7) rotated by static macro-generated code —
// rocprof showed VGPR_Count=52 for the array version, impossible unless the
// rings were in scratch (rule #20). launch_bounds(192,1) frees the allocator.
// + fused penalty (wave 2) + fused mean via atomicAdd.
// ---------------------------------------------------------------------------
__global__ __launch_bounds__(192, 1) void k_ctc(
    const unsigned short* __restrict__ Wt16, const float* __restrict__ Wb,
    const int* __restrict__ targets, const int* __restrict__ ilen,
    const int* __restrict__ tlen, const int* __restrict__ pred,
    float* __restrict__ out) {
  __shared__ float Bo[64], Be[64], BTs, penv;
  __shared__ int ts[SS];
  const int n = blockIdx.x;
  const int tid = threadIdx.x;
  const int wid = tid >> 6;
  const int l = tid & 63;

  const int Lm1 = __builtin_amdgcn_readfirstlane(ilen[n]) - 1;
  const int Ltg = __builtin_amdgcn_readfirstlane(tlen[n]);

  float fe0 = NEGF, fe1 = NEGF, fa0 = NEGF;
  float s0L = NEGF, s1L = NEGF;  // snapshot (Lm1 < 512), log2

  if (wid == 0) {
    // ---------------- forward wave: t = 0 .. 511 ----------------
    const int tgt = targets[n * SS + l];
    const int tprev = __shfl_up(tgt, 1);
    const float skipf = ((l == 0) || (tgt != tprev)) ? 1.0f : 0.0f;
    const uint2* bt = (const uint2*)(Wt16 + (size_t)(n * 64 + l) * TT);
    const float4* bb = (const float4*)(Wb + (size_t)n * TT);

    uint2 r0 = bt[0], r1 = bt[1], r2 = bt[2], r3 = bt[3];
    uint2 r4 = bt[4], r5 = bt[5], r6 = bt[6], r7 = bt[7];
    float4 q0 = bb[0], q1 = bb[1], q2 = bb[2], q3 = bb[3];
    float4 q4 = bb[4], q5 = bb[5], q6 = bb[6], q7 = bb[7];

    float Q0 = 0.0f, Q1 = 0.0f, Qa = 1.0f;
    int E = 0, Ea = 0, dEnb = 0, dEa = 0;
    float sQ0 = 0.0f, sQ1 = 0.0f;
    int sE = 0;

#define FSTEP(WTv, WBv)                              \
    {                                                \
      const float a0f = ldx(Qa, dEa);                \
      const float up0 = dpp_shr1(Q0, a0f);           \
      const float up1 = dpp_shr1(Q1, 0.0f);          \
      const float uu = fmaf(skipf, up1, up0);        \
      const float us = ldx(uu, dEnb);                \
      const float n1 = (Q1 + us) * (WTv);            \
      const float n0 = (Q0 + Q1) * (WBv);            \
      Qa *= (WBv);                                   \
      Q0 = n0;                                       \
      Q1 = n1;                                       \
    }
#define FRENORM                                               \
    {                                                         \
      const float mq = fmaxf(Q0, Q1);                         \
      const int eo = (mq > 0.0f)                              \
          ? (E + (((__float_as_int(mq) >> 23) & 255) - 127))  \
          : SMALLE;                                           \
      const int en = dpp_shr1_i(eo, SMALLE);                  \
      int En = (eo > en) ? eo : en;                           \
      if (En == SMALLE) En = E;                               \
      const int sh = E - En;                                  \
      Q0 = ldx(Q0, sh);                                       \
      Q1 = ldx(Q1, sh);                                       \
      E = En;                                                 \
      const int Eup = dpp_shr1_i(E, E);                       \
      dEnb = Eup - E;                                         \
      const int exa = ((__float_as_int(Qa) >> 23) & 255) - 127; \
      Ea += exa;                                              \
      Qa = ldx(Qa, -exa);                                     \
      dEa = Ea - E;                                           \
    }
#define FCHUNK(RW, RB, cc)                                        \
    {                                                             \
      const uint2 wt4 = RW;                                       \
      const float4 wb4 = RB;                                      \
      RW = bt[(cc) + 8];   /* overshoot stays inside the strip */ \
      RB = bb[(cc) + 8];                                          \
      if (__builtin_expect((unsigned)(Lm1 - (cc) * 4) < 4u, 0)) { \
        FSTEP(BF_LO(wt4.x), wb4.x);                               \
        if ((cc) * 4 + 0 == Lm1) { sQ0 = Q0; sQ1 = Q1; sE = E; }  \
        FSTEP(BF_HI(wt4.x), wb4.y);                               \
        if ((cc) * 4 + 1 == Lm1) { sQ0 = Q0; sQ1 = Q1; sE = E; }  \
        FSTEP(BF_LO(wt4.y), wb4.z);                               \
        if ((cc) * 4 + 2 == Lm1) { sQ0 = Q0; sQ1 = Q1; sE = E; }  \
        FSTEP(BF_HI(wt4.y), wb4.w);                               \
        if ((cc) * 4 + 3 == Lm1) { sQ0 = Q0; sQ1 = Q1; sE = E; }  \
      } else {                                                    \
        FSTEP(BF_LO(wt4.x), wb4.x);                               \
        FSTEP(BF_HI(wt4.x), wb4.y);                               \
        FSTEP(BF_LO(wt4.y), wb4.z);                               \
        FSTEP(BF_HI(wt4.y), wb4.w);                               \
      }                                                           \
      FRENORM;                                                    \
    }

    for (int g = 0; g < 16; ++g) {
      const int c0 = g * 8;
      FCHUNK(r0, q0, c0 + 0);
      FCHUNK(r1, q1, c0 + 1);
      FCHUNK(r2, q2, c0 + 2);
      FCHUNK(r3, q3, c0 + 3);
      FCHUNK(r4, q4, c0 + 4);
      FCHUNK(r5, q5, c0 + 5);
      FCHUNK(r6, q6, c0 + 6);
      FCHUNK(r7, q7, c0 + 7);
    }
#undef FCHUNK
#undef FSTEP
#undef FRENORM
    const float fE = (float)E;
    fe0 = (Q0 > 0.0f) ? (log2i(Q0) + fE) : NEGF;
    fe1 = (Q1 > 0.0f) ? (log2i(Q1) + fE) : NEGF;
    fa0 = (Qa > 0.0f) ? (log2i(Qa) + (float)Ea) : NEGF;
    s0L = (sQ0 > 0.0f) ? (log2i(sQ0) + (float)sE) : NEGF;
    s1L = (sQ1 > 0.0f) ? (log2i(sQ1) + (float)sE) : NEGF;
  } else if (wid == 1) {
    // ---------------- backward wave: t = 1023 .. 512 ----------------
    const int m = 63 - l;
    const int tm = targets[n * SS + m];
    const int tmp = __shfl_up(tm, 1);  // lane l-1 holds m+1
    const float skipbf = ((l > 0) && (tm != tmp)) ? 1.0f : 0.0f;
    const uint2* bt = (const uint2*)(Wt16 + (size_t)(n * 64 + m) * TT);
    const float4* bb = (const float4*)(Wb + (size_t)n * TT);

    uint2 r0 = bt[255], r1 = bt[254], r2 = bt[253], r3 = bt[252];
    uint2 r4 = bt[251], r5 = bt[250], r6 = bt[249], r7 = bt[248];
    float4 q0 = bb[255], q1 = bb[254], q2 = bb[253], q3 = bb[252];
    float4 q4 = bb[251], q5 = bb[250], q6 = bb[249], q7 = bb[248];

    float Qd0 = 0.0f, Qd1 = 0.0f, QaT = 0.0f;
    int Eb = 0, EaT = 0, dEnb = 0, dEa = 0;

#define BSTEP(WTv, WBv)                              \
    {                                                \
      const float aTf = ldx(QaT, dEa);               \
      const float nd0 = dpp_shr1(Qd0, aTf);          \
      const float nd1 = dpp_shr1(Qd1, 0.0f);         \
      const float uu = fmaf(skipbf, nd1, nd0);       \
      const float us = ldx(uu, dEnb);                \
      const float n1 = (Qd1 + us) * (WTv);           \
      const float n0 = (Qd0 + Qd1) * (WBv);          \
      QaT *= (WBv);                                  \
      Qd0 = n0;                                      \
      Qd1 = n1;                                      \
    }
#define BINIT(WTv, WBv)                              \
    {                                                \
      Qd0 = (m == Ltg) ? (WBv) : 0.0f;               \
      Qd1 = (m == Ltg - 1) ? (WTv) : 0.0f;           \
      QaT = (Ltg == 64) ? (WBv) : 0.0f;              \
      Eb = 0; EaT = 0; dEnb = 0; dEa = 0;            \
    }
#define BRENORM                                               \
    {                                                         \
      const float mq = fmaxf(Qd0, Qd1);                       \
      const int eo = (mq > 0.0f)                              \
          ? (Eb + (((__float_as_int(mq) >> 23) & 255) - 127)) \
          : SMALLE;                                           \
      const int en = dpp_shr1_i(eo, SMALLE);                  \
      int En = (eo > en) ? eo : en;                           \
      if (En == SMALLE) En = Eb;                              \
      const int sh = Eb - En;                                 \
      Qd0 = ldx(Qd0, sh);                                     \
      Qd1 = ldx(Qd1, sh);                                     \
      Eb = En;                                                \
      const int Eup = dpp_shr1_i(Eb, Eb);                     \
      dEnb = Eup - Eb;                                        \
      if (QaT > 0.0f) {                                       \
        const int exa = ((__float_as_int(QaT) >> 23) & 255) - 127; \
        EaT += exa;                                           \
        QaT = ldx(QaT, -exa);                                 \
      }                                                       \
      dEa = EaT - Eb;                                         \
    }
#define BCHUNK(RW, RB, cs)                                          \
    {                                                               \
      const uint2 wt4 = RW;                                         \
      const float4 wb4 = RB;                                        \
      RW = bt[255 - (cs) - 8];                                      \
      RB = bb[255 - (cs) - 8];                                      \
      const int thi = 1023 - 4 * (cs);                              \
      if (__builtin_expect((unsigned)(thi - Lm1) < 4u, 0)) {        \
        if (thi - 0 == Lm1) BINIT(BF_HI(wt4.y), wb4.w)              \
        else BSTEP(BF_HI(wt4.y), wb4.w);                            \
        if (thi - 1 == Lm1) BINIT(BF_LO(wt4.y), wb4.z)              \
        else BSTEP(BF_LO(wt4.y), wb4.z);                            \
        if (thi - 2 == Lm1) BINIT(BF_HI(wt4.x), wb4.y)              \
        else BSTEP(BF_HI(wt4.x), wb4.y);                            \
        if (thi - 3 == Lm1) BINIT(BF_LO(wt4.x), wb4.x)              \
        else BSTEP(BF_LO(wt4.x), wb4.x);                            \
      } else {                                                      \
        BSTEP(BF_HI(wt4.y), wb4.w);                                 \
        BSTEP(BF_LO(wt4.y), wb4.z);                                 \
        BSTEP(BF_HI(wt4.x), wb4.y);                                 \
        BSTEP(BF_LO(wt4.x), wb4.x);                                 \
      }                                                             \
      BRENORM;                                                      \
    }

    for (int g = 0; g < 16; ++g) {
      const int c0 = g * 8;
      BCHUNK(r0, q0, c0 + 0);
      BCHUNK(r1, q1, c0 + 1);
      BCHUNK(r2, q2, c0 + 2);
      BCHUNK(r3, q3, c0 + 3);
      BCHUNK(r4, q4, c0 + 4);
      BCHUNK(r5, q5, c0 + 5);
      BCHUNK(r6, q6, c0 + 6);
      BCHUNK(r7, q7, c0 + 7);
    }
#undef BCHUNK
#undef BSTEP
#undef BINIT
#undef BRENORM

    // convert to log2; boundary combine step (R4-verified shape)
    const float fEb = (float)Eb;
    const float d0L = (Qd0 > 0.0f) ? (log2i(Qd0) + fEb) : NEGF;
    const float d1L = (Qd1 > 0.0f) ? (log2i(Qd1) + fEb) : NEGF;
    const float aTL = (QaT > 0.0f) ? (log2i(QaT) + (float)EaT) : NEGF;
    const float nd0 = dpp_shr1(d0L, aTL);
    const float nd1 = dpp_shr1(d1L, NEGF);
    const float skz = ((l > 0) && (tm != tmp)) ? nd1 : NEGF;
    Bo[m] = lse3(d1L, nd0, skz);
    Be[m] = lse2(d0L, d1L);
    if (l == 0) BTs = aTL;
  } else {
    // ---------------- penalty wave ----------------
    const int tv = targets[n * SS + l];
    const bool tf = (l < Ltg) && (tv >= 1) && (tv <= 8);
    const unsigned long long tmk = __ballot(tf);
    const int tcnt = __popcll(tmk);
    if (tf) ts[__popcll(tmk & ((1ull << l) - 1ull))] = tv;

    const int L_in = Lm1 + 1;
    int mism = 0;
    int prevc = -1;
    int base = 0;
#pragma unroll 4
    for (int c = 0; c < TT / 64; ++c) {
      const int t = c * 64 + l;
      int p = pred[n * TT + t];
      if (t >= L_in) p = 0;
      int pp = __shfl_up(p, 1);
      if (l == 0) pp = prevc;
      const bool keep = (p != pp) && (p >= 1) && (p <= 8);
      const unsigned long long mk = __ballot(keep);
      const int pos = base + __popcll(mk & ((1ull << l) - 1ull));
      if (keep && (pos >= tcnt || ts[pos] != p)) mism = 1;
      base += __popcll(mk);
      prevc = __shfl(p, 63);
    }
    if (base != tcnt) mism = 1;
    if (__any(mism)) mism = 1;
    if (l == 0) penv = mism ? 1.0f : 0.0f;
  }

  __syncthreads();

  if (wid == 0) {
    float loss;
    if (Lm1 >= 512) {
      const float to_ = fe1 + Bo[l];                         // u = 2l+1
      const float te_ = fe0 + ((l < 63) ? Be[l + 1] : BTs);  // u = 2l+2
      const float t0_ = (l == 0) ? (fa0 + Be[0]) : NEGF;     // u = 0
      float mx = fmaxf(fmaxf(to_, te_), t0_);
#pragma unroll
      for (int off = 32; off; off >>= 1) mx = fmaxf(mx, __shfl_xor(mx, off));
      float s = exp2i(to_ - mx) + exp2i(te_ - mx) +
                ((l == 0) ? exp2i(t0_ - mx) : 0.0f);
#pragma unroll
      for (int off = 32; off; off >>= 1) s += __shfl_xor(s, off);
      loss = -(mx + log2i(s)) * LN2F;
    } else {
      const float pA = __shfl(s0L, Ltg - 1);  // alpha[2*Ltg]
      const float pB = __shfl(s1L, Ltg - 1);  // alpha[2*Ltg-1]
      loss = -lse2(pA, pB) * LN2F;
    }
    if (loss > 1e20f) loss = 0.0f;
    if (!(loss <= 1e20f)) loss = 0.0f;  // NaN guard
    if (l == 0) atomicAdd(out, (loss + penv) * (1.0f / NN));
  }
}

extern "C" void kernel_launch(void* const* d_in, const int* in_sizes, int n_in,
                              void* d_out, int out_size, void* d_ws,
                              size_t ws_size, hipStream_t stream) {
  const float* log_probs = (const float*)d_in[0];  // (T,N,C) f32
  const int* targets = (const int*)d_in[1];        // (N,S) i32
  const int* input_lengths = (const int*)d_in[2];  // (N,) i32
  const int* target_lengths = (const int*)d_in[3]; // (N,) i32
  float* out = (float*)d_out;

  // workspace layout
  unsigned short* Wt16 = (unsigned short*)d_ws;      // [N*64][T] bf16 (8.4 MB)
  float* Wb = (float*)(Wt16 + (size_t)NN * 64 * TT); // [N][T] f32 (256 KB)
  int* pred = (int*)(Wb + (size_t)NN * TT);          // [N][T] i32 (256 KB)

  k_rowpass<<<NN * (TT / TCH), 256, 0, stream>>>(log_probs, targets, Wt16, Wb,
                                                 pred, out);
  k_ctc<<<NN, 192, 0, stream>>>(Wt16, Wb, targets, input_lengths,
                                target_lengths, pred, out);
}

// Round 13
// 50.368 us; speedup vs baseline: 5.6324x; 1.0706x over previous
//
#include <hip/hip_runtime.h>
#include <hip/hip_bf16.h>
#include <cstdint>
#include <cstddef>

#define TT 1024
#define NN 64
#define CC 512
#define SS 64
#define TCH 32  // t-chunk per rowpass block
#define NEGF (-1e30f)
#define LN2F 0.6931471805599453f
#define SMALLE (-0x40000000)

__device__ __forceinline__ float exp2i(float x) { return __builtin_amdgcn_exp2f(x); }
__device__ __forceinline__ float log2i(float x) { return __builtin_amdgcn_logf(x); }

__device__ __forceinline__ float ldx(float x, int e) {
#if __has_builtin(__builtin_amdgcn_ldexpf)
  return __builtin_amdgcn_ldexpf(x, e);
#else
  return ldexpf(x, e);
#endif
}

// log-sum-exp in log2 domain (final combine only)
__device__ __forceinline__ float lse2(float x, float y) {
  float m = fmaxf(x, y);
  float d = fabsf(x - y);
  return m + log2i(1.0f + exp2i(-d));
}
__device__ __forceinline__ float lse3(float x, float y, float z) {
  float m = fmaxf(fmaxf(x, y), z);
  float s = exp2i(x - m) + exp2i(y - m) + exp2i(z - m);
  return m + log2i(s);
}

// lane l gets lane l-1's value; lane 0 gets `oldv` (DPP wave_shr:1) — HW-verified R2/R5/R7.
__device__ __forceinline__ float dpp_shr1(float x, float oldv) {
  int r = __builtin_amdgcn_update_dpp(__float_as_int(oldv), __float_as_int(x),
                                      0x138, 0xF, 0xF, false);
  return __int_as_float(r);
}
__device__ __forceinline__ int dpp_shr1_i(int x, int oldv) {
  return __builtin_amdgcn_update_dpp(oldv, x, 0x138, 0xF, 0xF, false);
}

// one u64-max DPP reduction step (old = self: uncovered lanes keep own key)
template <int CTRL>
__device__ __forceinline__ unsigned long long dpp_umax64(unsigned long long k) {
  const int lo = (int)(unsigned)k;
  const int hi = (int)(unsigned)(k >> 32);
  const int slo = __builtin_amdgcn_update_dpp(lo, lo, CTRL, 0xF, 0xF, false);
  const int shi = __builtin_amdgcn_update_dpp(hi, hi, CTRL, 0xF, 0xF, false);
  const unsigned long long o =
      ((unsigned long long)(unsigned)shi << 32) | (unsigned)slo;
  return o > k ? o : k;
}

// argmax key: monotone for log-softmax values (all < 0). Low bits: 511-idx
// so max picks the FIRST index on exact ties.  [HW-verified R7]
__device__ __forceinline__ unsigned long long akey(float v, int idx) {
  return ((unsigned long long)(~__float_as_uint(v)) << 32) |
         (unsigned)(511 - idx);
}
__device__ __forceinline__ unsigned long long umax64(unsigned long long a,
                                                     unsigned long long b) {
  return a > b ? a : b;
}

// f32 -> bf16 RNE (inputs are finite positive probs)
__device__ __forceinline__ unsigned bf16rne(float f) {
  unsigned u = __float_as_uint(f);
  return (u + 0x7FFFu + ((u >> 16) & 1u)) >> 16;
}

// bf16 halves of a u32 -> f32
#define BF_LO(r) __uint_as_float((r) << 16)
#define BF_HI(r) __uint_as_float((r) & 0xFFFF0000u)

// ---------------------------------------------------------------------------
// Kernel 1: fused row pass (R9/R12-verbatim). Block = one n x 32 t, 4 waves x
// 8 rows. DPP-u64 argmax -> pred; bf16 linear target weights transposed:
// Wt16[(n*64+s)][t]; blank f32 -> Wb[n][t]. Block 0 zeroes out[0].
// ---------------------------------------------------------------------------
__global__ __launch_bounds__(256) void k_rowpass(
    const float* __restrict__ lp, const int* __restrict__ targets,
    unsigned short* __restrict__ Wt16, float* __restrict__ Wb,
    int* __restrict__ pred, float* __restrict__ out) {
  __shared__ float rows[4][CC];
  __shared__ float Gs[TCH][65];
  __shared__ float Gsb[TCH];
  const int tid = threadIdx.x;
  const int wid = tid >> 6;
  const int l = tid & 63;
  const int n = blockIdx.x & 63;
  const int tc = blockIdx.x >> 6;  // t-chunk of 32

  if (blockIdx.x == 0 && tid == 0) out[0] = 0.0f;

  const int tgt = targets[n * SS + l];

  for (int i = 0; i < 8; ++i) {
    const int tl = wid * 8 + i;  // local t in [0,32)
    const int t = tc * TCH + tl;
    const float* row = lp + ((size_t)t * NN + n) * CC;
    const float4 v0 = ((const float4*)row)[l];
    const float4 v1 = ((const float4*)row)[l + 64];
    ((float4*)rows[wid])[l] = v0;
    ((float4*)rows[wid])[l + 64] = v1;

    const unsigned long long ka =
        umax64(akey(v0.x, 4 * l), akey(v0.y, 4 * l + 1));
    const unsigned long long kb =
        umax64(akey(v0.z, 4 * l + 2), akey(v0.w, 4 * l + 3));
    const unsigned long long kc =
        umax64(akey(v1.x, 256 + 4 * l), akey(v1.y, 256 + 4 * l + 1));
    const unsigned long long kd =
        umax64(akey(v1.z, 256 + 4 * l + 2), akey(v1.w, 256 + 4 * l + 3));
    unsigned long long k = umax64(umax64(ka, kb), umax64(kc, kd));
    k = dpp_umax64<0x111>(k);  // row_shr:1
    k = dpp_umax64<0x112>(k);  // row_shr:2
    k = dpp_umax64<0x114>(k);  // row_shr:4
    k = dpp_umax64<0x118>(k);  // row_shr:8
    k = dpp_umax64<0x142>(k);  // row_bcast:15
    k = dpp_umax64<0x143>(k);  // row_bcast:31

    const float gv = rows[wid][tgt];
    Gs[tl][l] = __expf(gv);  // linear p(tgt)
    if (l == 63) pred[n * TT + t] = 511 - (int)(unsigned)k;
    if (l == 0) Gsb[tl] = __expf(v0.x);  // linear p(blank)
  }
  __syncthreads();

  // transpose store: thread (l, q) packs 8 t's (bf16, 16B) for strip l
  const int q = tid >> 6;
  uint4 wv;
  wv.x = bf16rne(Gs[q * 8 + 0][l]) | (bf16rne(Gs[q * 8 + 1][l]) << 16);
  wv.y = bf16rne(Gs[q * 8 + 2][l]) | (bf16rne(Gs[q * 8 + 3][l]) << 16);
  wv.z = bf16rne(Gs[q * 8 + 4][l]) | (bf16rne(Gs[q * 8 + 5][l]) << 16);
  wv.w = bf16rne(Gs[q * 8 + 6][l]) | (bf16rne(Gs[q * 8 + 7][l]) << 16);
  *(uint4*)(Wt16 + (size_t)(n * 64 + l) * TT + tc * TCH + q * 8) = wv;
  if (tid < TCH) Wb[(size_t)n * TT + tc * TCH + tid] = Gsb[tid];
}

// ---------------------------------------------------------------------------
// Kernel 2: CTC fwd/bwd in LINEAR domain with per-lane exponent frames.
// FSTEP/BSTEP macros R9/R12-VERBATIM. ONE change: renorm runs every OTHER
// chunk (every 8 steps) — exactly round 5's HW-verified configuration
// (absmax 0.0). Saves ~18 chain VALU ops per 8 steps (~16% of issue load).
// Frames stay lockstep across lanes (renorms are synchronized); worst-case
// intra-lane drift per interval 2^-184 -> flushes only negligible mass.
// + fused penalty (wave 2) + fused mean via atomicAdd.
// ---------------------------------------------------------------------------
__global__ __launch_bounds__(192, 1) void k_ctc(
    const unsigned short* __restrict__ Wt16, const float* __restrict__ Wb,
    const int* __restrict__ targets, const int* __restrict__ ilen,
    const int* __restrict__ tlen, const int* __restrict__ pred,
    float* __restrict__ out) {
  __shared__ float Bo[64], Be[64], BTs, penv;
  __shared__ int ts[SS];
  const int n = blockIdx.x;
  const int tid = threadIdx.x;
  const int wid = tid >> 6;
  const int l = tid & 63;

  const int Lm1 = __builtin_amdgcn_readfirstlane(ilen[n]) - 1;
  const int Ltg = __builtin_amdgcn_readfirstlane(tlen[n]);

  float fe0 = NEGF, fe1 = NEGF, fa0 = NEGF;
  float s0L = NEGF, s1L = NEGF;  // snapshot (Lm1 < 512), log2

  if (wid == 0) {
    // ---------------- forward wave: t = 0 .. 511 ----------------
    const int tgt = targets[n * SS + l];
    const int tprev = __shfl_up(tgt, 1);
    const float skipf = ((l == 0) || (tgt != tprev)) ? 1.0f : 0.0f;
    const uint2* bt = (const uint2*)(Wt16 + (size_t)(n * 64 + l) * TT);
    const float4* bb = (const float4*)(Wb + (size_t)n * TT);

    uint2 r0 = bt[0], r1 = bt[1], r2 = bt[2], r3 = bt[3];
    uint2 r4 = bt[4], r5 = bt[5], r6 = bt[6], r7 = bt[7];
    float4 q0 = bb[0], q1 = bb[1], q2 = bb[2], q3 = bb[3];
    float4 q4 = bb[4], q5 = bb[5], q6 = bb[6], q7 = bb[7];

    float Q0 = 0.0f, Q1 = 0.0f, Qa = 1.0f;
    int E = 0, Ea = 0, dEnb = 0, dEa = 0;
    float sQ0 = 0.0f, sQ1 = 0.0f;
    int sE = 0;

#define FSTEP(WTv, WBv)                              \
    {                                                \
      const float a0f = ldx(Qa, dEa);                \
      const float up0 = dpp_shr1(Q0, a0f);           \
      const float up1 = dpp_shr1(Q1, 0.0f);          \
      const float uu = fmaf(skipf, up1, up0);        \
      const float us = ldx(uu, dEnb);                \
      const float n1 = (Q1 + us) * (WTv);            \
      const float n0 = (Q0 + Q1) * (WBv);            \
      Qa *= (WBv);                                   \
      Q0 = n0;                                       \
      Q1 = n1;                                       \
    }
#define FRENORM                                               \
    {                                                         \
      const float mq = fmaxf(Q0, Q1);                         \
      const int eo = (mq > 0.0f)                              \
          ? (E + (((__float_as_int(mq) >> 23) & 255) - 127))  \
          : SMALLE;                                           \
      const int en = dpp_shr1_i(eo, SMALLE);                  \
      int En = (eo > en) ? eo : en;                           \
      if (En == SMALLE) En = E;                               \
      const int sh = E - En;                                  \
      Q0 = ldx(Q0, sh);                                       \
      Q1 = ldx(Q1, sh);                                       \
      E = En;                                                 \
      const int Eup = dpp_shr1_i(E, E);                       \
      dEnb = Eup - E;                                         \
      const int exa = ((__float_as_int(Qa) >> 23) & 255) - 127; \
      Ea += exa;                                              \
      Qa = ldx(Qa, -exa);                                     \
      dEa = Ea - E;                                           \
    }
#define FCHUNK(RW, RB, cc, RN)                                    \
    {                                                             \
      const uint2 wt4 = RW;                                       \
      const float4 wb4 = RB;                                      \
      RW = bt[(cc) + 8];   /* overshoot stays inside the strip */ \
      RB = bb[(cc) + 8];                                          \
      if (__builtin_expect((unsigned)(Lm1 - (cc) * 4) < 4u, 0)) { \
        FSTEP(BF_LO(wt4.x), wb4.x);                               \
        if ((cc) * 4 + 0 == Lm1) { sQ0 = Q0; sQ1 = Q1; sE = E; }  \
        FSTEP(BF_HI(wt4.x), wb4.y);                               \
        if ((cc) * 4 + 1 == Lm1) { sQ0 = Q0; sQ1 = Q1; sE = E; }  \
        FSTEP(BF_LO(wt4.y), wb4.z);                               \
        if ((cc) * 4 + 2 == Lm1) { sQ0 = Q0; sQ1 = Q1; sE = E; }  \
        FSTEP(BF_HI(wt4.y), wb4.w);                               \
        if ((cc) * 4 + 3 == Lm1) { sQ0 = Q0; sQ1 = Q1; sE = E; }  \
      } else {                                                    \
        FSTEP(BF_LO(wt4.x), wb4.x);                               \
        FSTEP(BF_HI(wt4.x), wb4.y);                               \
        FSTEP(BF_LO(wt4.y), wb4.z);                               \
        FSTEP(BF_HI(wt4.y), wb4.w);                               \
      }                                                           \
      if (RN) FRENORM;                                            \
    }

    for (int g = 0; g < 16; ++g) {
      const int c0 = g * 8;
      FCHUNK(r0, q0, c0 + 0, 0);
      FCHUNK(r1, q1, c0 + 1, 1);
      FCHUNK(r2, q2, c0 + 2, 0);
      FCHUNK(r3, q3, c0 + 3, 1);
      FCHUNK(r4, q4, c0 + 4, 0);
      FCHUNK(r5, q5, c0 + 5, 1);
      FCHUNK(r6, q6, c0 + 6, 0);
      FCHUNK(r7, q7, c0 + 7, 1);
    }
#undef FCHUNK
#undef FSTEP
#undef FRENORM
    const float fE = (float)E;
    fe0 = (Q0 > 0.0f) ? (log2i(Q0) + fE) : NEGF;
    fe1 = (Q1 > 0.0f) ? (log2i(Q1) + fE) : NEGF;
    fa0 = (Qa > 0.0f) ? (log2i(Qa) + (float)Ea) : NEGF;
    s0L = (sQ0 > 0.0f) ? (log2i(sQ0) + (float)sE) : NEGF;
    s1L = (sQ1 > 0.0f) ? (log2i(sQ1) + (float)sE) : NEGF;
  } else if (wid == 1) {
    // ---------------- backward wave: t = 1023 .. 512 ----------------
    const int m = 63 - l;
    const int tm = targets[n * SS + m];
    const int tmp = __shfl_up(tm, 1);  // lane l-1 holds m+1
    const float skipbf = ((l > 0) && (tm != tmp)) ? 1.0f : 0.0f;
    const uint2* bt = (const uint2*)(Wt16 + (size_t)(n * 64 + m) * TT);
    const float4* bb = (const float4*)(Wb + (size_t)n * TT);

    uint2 r0 = bt[255], r1 = bt[254], r2 = bt[253], r3 = bt[252];
    uint2 r4 = bt[251], r5 = bt[250], r6 = bt[249], r7 = bt[248];
    float4 q0 = bb[255], q1 = bb[254], q2 = bb[253], q3 = bb[252];
    float4 q4 = bb[251], q5 = bb[250], q6 = bb[249], q7 = bb[248];

    float Qd0 = 0.0f, Qd1 = 0.0f, QaT = 0.0f;
    int Eb = 0, EaT = 0, dEnb = 0, dEa = 0;

#define BSTEP(WTv, WBv)                              \
    {                                                \
      const float aTf = ldx(QaT, dEa);               \
      const float nd0 = dpp_shr1(Qd0, aTf);          \
      const float nd1 = dpp_shr1(Qd1, 0.0f);         \
      const float uu = fmaf(skipbf, nd1, nd0);       \
      const float us = ldx(uu, dEnb);                \
      const float n1 = (Qd1 + us) * (WTv);           \
      const float n0 = (Qd0 + Qd1) * (WBv);          \
      QaT *= (WBv);                                  \
      Qd0 = n0;                                      \
      Qd1 = n1;                                      \
    }
#define BINIT(WTv, WBv)                              \
    {                                                \
      Qd0 = (m == Ltg) ? (WBv) : 0.0f;               \
      Qd1 = (m == Ltg - 1) ? (WTv) : 0.0f;           \
      QaT = (Ltg == 64) ? (WBv) : 0.0f;              \
      Eb = 0; EaT = 0; dEnb = 0; dEa = 0;            \
    }
#define BRENORM                                               \
    {                                                         \
      const float mq = fmaxf(Qd0, Qd1);                       \
      const int eo = (mq > 0.0f)                              \
          ? (Eb + (((__float_as_int(mq) >> 23) & 255) - 127)) \
          : SMALLE;                                           \
      const int en = dpp_shr1_i(eo, SMALLE);                  \
      int En = (eo > en) ? eo : en;                           \
      if (En == SMALLE) En = Eb;                              \
      const int sh = Eb - En;                                 \
      Qd0 = ldx(Qd0, sh);                                     \
      Qd1 = ldx(Qd1, sh);                                     \
      Eb = En;                                                \
      const int Eup = dpp_shr1_i(Eb, Eb);                     \
      dEnb = Eup - Eb;                                        \
      if (QaT > 0.0f) {                                       \
        const int exa = ((__float_as_int(QaT) >> 23) & 255) - 127; \
        EaT += exa;                                           \
        QaT = ldx(QaT, -exa);                                 \
      }                                                       \
      dEa = EaT - Eb;                                         \
    }
#define BCHUNK(RW, RB, cs, RN)                                      \
    {                                                               \
      const uint2 wt4 = RW;                                         \
      const float4 wb4 = RB;                                        \
      RW = bt[255 - (cs) - 8];                                      \
      RB = bb[255 - (cs) - 8];                                      \
      const int thi = 1023 - 4 * (cs);                              \
      if (__builtin_expect((unsigned)(thi - Lm1) < 4u, 0)) {        \
        if (thi - 0 == Lm1) BINIT(BF_HI(wt4.y), wb4.w)              \
        else BSTEP(BF_HI(wt4.y), wb4.w);                            \
        if (thi - 1 == Lm1) BINIT(BF_LO(wt4.y), wb4.z)              \
        else BSTEP(BF_LO(wt4.y), wb4.z);                            \
        if (thi - 2 == Lm1) BINIT(BF_HI(wt4.x), wb4.y)              \
        else BSTEP(BF_HI(wt4.x), wb4.y);                            \
        if (thi - 3 == Lm1) BINIT(BF_LO(wt4.x), wb4.x)              \
        else BSTEP(BF_LO(wt4.x), wb4.x);                            \
      } else {                                                      \
        BSTEP(BF_HI(wt4.y), wb4.w);                                 \
        BSTEP(BF_LO(wt4.y), wb4.z);                                 \
        BSTEP(BF_HI(wt4.x), wb4.y);                                 \
        BSTEP(BF_LO(wt4.x), wb4.x);                                 \
      }                                                             \
      if (RN) BRENORM;                                              \
    }

    for (int g = 0; g < 16; ++g) {
      const int c0 = g * 8;
      BCHUNK(r0, q0, c0 + 0, 0);
      BCHUNK(r1, q1, c0 + 1, 1);
      BCHUNK(r2, q2, c0 + 2, 0);
      BCHUNK(r3, q3, c0 + 3, 1);
      BCHUNK(r4, q4, c0 + 4, 0);
      BCHUNK(r5, q5, c0 + 5, 1);
      BCHUNK(r6, q6, c0 + 6, 0);
      BCHUNK(r7, q7, c0 + 7, 1);
    }
#undef BCHUNK
#undef BSTEP
#undef BINIT
#undef BRENORM

    // convert to log2; boundary combine step (R4-verified shape)
    const float fEb = (float)Eb;
    const float d0L = (Qd0 > 0.0f) ? (log2i(Qd0) + fEb) : NEGF;
    const float d1L = (Qd1 > 0.0f) ? (log2i(Qd1) + fEb) : NEGF;
    const float aTL = (QaT > 0.0f) ? (log2i(QaT) + (float)EaT) : NEGF;
    const float nd0 = dpp_shr1(d0L, aTL);
    const float nd1 = dpp_shr1(d1L, NEGF);
    const float skz = ((l > 0) && (tm != tmp)) ? nd1 : NEGF;
    Bo[m] = lse3(d1L, nd0, skz);
    Be[m] = lse2(d0L, d1L);
    if (l == 0) BTs = aTL;
  } else {
    // ---------------- penalty wave ----------------
    const int tv = targets[n * SS + l];
    const bool tf = (l < Ltg) && (tv >= 1) && (tv <= 8);
    const unsigned long long tmk = __ballot(tf);
    const int tcnt = __popcll(tmk);
    if (tf) ts[__popcll(tmk & ((1ull << l) - 1ull))] = tv;

    const int L_in = Lm1 + 1;
    int mism = 0;
    int prevc = -1;
    int base = 0;
#pragma unroll 4
    for (int c = 0; c < TT / 64; ++c) {
      const int t = c * 64 + l;
      int p = pred[n * TT + t];
      if (t >= L_in) p = 0;
      int pp = __shfl_up(p, 1);
      if (l == 0) pp = prevc;
      const bool keep = (p != pp) && (p >= 1) && (p <= 8);
      const unsigned long long mk = __ballot(keep);
      const int pos = base + __popcll(mk & ((1ull << l) - 1ull));
      if (keep && (pos >= tcnt || ts[pos] != p)) mism = 1;
      base += __popcll(mk);
      prevc = __shfl(p, 63);
    }
    if (base != tcnt) mism = 1;
    if (__any(mism)) mism = 1;
    if (l == 0) penv = mism ? 1.0f : 0.0f;
  }

  __syncthreads();

  if (wid == 0) {
    float loss;
    if (Lm1 >= 512) {
      const float to_ = fe1 + Bo[l];                         // u = 2l+1
      const float te_ = fe0 + ((l < 63) ? Be[l + 1] : BTs);  // u = 2l+2
      const float t0_ = (l == 0) ? (fa0 + Be[0]) : NEGF;     // u = 0
      float mx = fmaxf(fmaxf(to_, te_), t0_);
#pragma unroll
      for (int off = 32; off; off >>= 1) mx = fmaxf(mx, __shfl_xor(mx, off));
      float s = exp2i(to_ - mx) + exp2i(te_ - mx) +
                ((l == 0) ? exp2i(t0_ - mx) : 0.0f);
#pragma unroll
      for (int off = 32; off; off >>= 1) s += __shfl_xor(s, off);
      loss = -(mx + log2i(s)) * LN2F;
    } else {
      const float pA = __shfl(s0L, Ltg - 1);  // alpha[2*Ltg]
      const float pB = __shfl(s1L, Ltg - 1);  // alpha[2*Ltg-1]
      loss = -lse2(pA, pB) * LN2F;
    }
    if (loss > 1e20f) loss = 0.0f;
    if (!(loss <= 1e20f)) loss = 0.0f;  // NaN guard
    if (l == 0) atomicAdd(out, (loss + penv) * (1.0f / NN));
  }
}

extern "C" void kernel_launch(void* const* d_in, const int* in_sizes, int n_in,
                              void* d_out, int out_size, void* d_ws,
                              size_t ws_size, hipStream_t stream) {
  const float* log_probs = (const float*)d_in[0];  // (T,N,C) f32
  const int* targets = (const int*)d_in[1];        // (N,S) i32
  const int* input_lengths = (const int*)d_in[2];  // (N,) i32
  const int* target_lengths = (const int*)d_in[3]; // (N,) i32
  float* out = (float*)d_out;

  // workspace layout
  unsigned short* Wt16 = (unsigned short*)d_ws;      // [N*64][T] bf16 (8.4 MB)
  float* Wb = (float*)(Wt16 + (size_t)NN * 64 * TT); // [N][T] f32 (256 KB)
  int* pred = (int*)(Wb + (size_t)NN * TT);          // [N][T] i32 (256 KB)

  k_rowpass<<<NN * (TT / TCH), 256, 0, stream>>>(log_probs, targets, Wt16, Wb,
                                                 pred, out);
  k_ctc<<<NN, 192, 0, stream>>>(Wt16, Wb, targets, input_lengths,
                                target_lengths, pred, out);
}